// Round 3
// baseline (2047.605 us; speedup 1.0000x reference)
//
#include <hip/hip_runtime.h>
#include <hip/hip_bf16.h>
#include <cstdint>

// Problem constants (ViT-Base, 14x14 window + CLS)
//  B=128, N=197, DIM=768, H=12, HD=64, NRD=732
#define BATCH 128
#define NTOK  197
#define NHEAD 12
#define HDIM  64
#define BIAS_PAD 256   // padded key stride for bias_full rows (attn reads kn up to 255)

// ---------------------------------------------------------------------------
// K0: densify relative-position bias:  bias_full[h][qn][kn(pad 256)] =
//     rpb_table[rel_idx[qn*197+kn]*12 + h]   (zeros in the pad region)
// ---------------------------------------------------------------------------
__global__ void bias_precompute(const float* __restrict__ rpb,
                                const int* __restrict__ rel_idx,
                                float* __restrict__ bias_full) {
    int idx = blockIdx.x * 256 + threadIdx.x;
    const int per_h = NTOK * BIAS_PAD;           // 50432
    if (idx >= NHEAD * per_h) return;
    int h   = idx / per_h;
    int rem = idx - h * per_h;
    int qn  = rem >> 8;
    int kn  = rem & 255;
    float v = 0.f;
    if (kn < NTOK) v = rpb[rel_idx[qn * NTOK + kn] * NHEAD + h];
    bias_full[idx] = v;
}

// ---------------------------------------------------------------------------
// fp32 NT GEMM:  C[m][n] = sum_k A[m][k] * W[n][k]  (K = 768), chunk of Mc rows
// 64x64 tile / 256-thread block, BK=16, 4x4 microtile. LDS tiles transposed
// [k][row] (pad 68) -> conflict-free ds_read_b128 in the inner loop.
// EPI=0: qkv epilogue -> scatter to q(*0.125)/k/v in [Bc,H,N,64]
// EPI=1: proj epilogue -> out[m][col] + bias
// ---------------------------------------------------------------------------
template <int EPI>
__global__ __launch_bounds__(256) void gemm_nt(
    const float* __restrict__ A, const float* __restrict__ W,
    const float* __restrict__ bias1, const float* __restrict__ bias2,
    float* __restrict__ out0, float* __restrict__ out1, float* __restrict__ out2,
    int Mc) {
    __shared__ float As[16][68];
    __shared__ float Bs[16][68];

    const int t  = threadIdx.x;
    const int tx = t & 15;        // column group
    const int ty = t >> 4;        // row group
    const int n0 = blockIdx.x * 64;
    const int m0 = blockIdx.y * 64;
    const int lrow = t >> 2;      // 0..63 staging row
    const int lcg  = t & 3;       // 0..3  staging k-group (4 floats)

    int arow = m0 + lrow; if (arow >= Mc) arow = Mc - 1;   // clamp tail reads
    const float* Ap = A + (size_t)arow * 768 + lcg * 4;
    const float* Wp = W + (size_t)(n0 + lrow) * 768 + lcg * 4;

    float acc[4][4] = {};

    for (int k0 = 0; k0 < 768; k0 += 16) {
        float4 a = *(const float4*)(Ap + k0);
        float4 w = *(const float4*)(Wp + k0);
        __syncthreads();
        As[lcg * 4 + 0][lrow] = a.x;  As[lcg * 4 + 1][lrow] = a.y;
        As[lcg * 4 + 2][lrow] = a.z;  As[lcg * 4 + 3][lrow] = a.w;
        Bs[lcg * 4 + 0][lrow] = w.x;  Bs[lcg * 4 + 1][lrow] = w.y;
        Bs[lcg * 4 + 2][lrow] = w.z;  Bs[lcg * 4 + 3][lrow] = w.w;
        __syncthreads();
#pragma unroll
        for (int dd = 0; dd < 16; dd++) {
            float4 a4 = *(const float4*)&As[dd][ty * 4];
            float4 b4 = *(const float4*)&Bs[dd][tx * 4];
            float av[4] = {a4.x, a4.y, a4.z, a4.w};
            float bv[4] = {b4.x, b4.y, b4.z, b4.w};
#pragma unroll
            for (int i = 0; i < 4; i++)
#pragma unroll
                for (int j = 0; j < 4; j++) acc[i][j] += av[i] * bv[j];
        }
    }

    if (EPI == 0) {
        // cols n0..n0+63 lie inside one (part, h) since n0 % 64 == 0
        const int part    = n0 / 768;              // 0=q 1=k 2=v
        const int within0 = n0 - part * 768;       // multiple of 64
        const int h       = within0 / 64;
        float bsum[4];
#pragma unroll
        for (int j = 0; j < 4; j++) {
            int wdx = within0 + tx * 4 + j;
            bsum[j] = (part == 0) ? bias1[wdx] : (part == 2 ? bias2[wdx] : 0.f);
        }
        const float scale = (part == 0) ? 0.125f : 1.f;   // 64^-0.5
        float* dst = (part == 0) ? out0 : (part == 1 ? out1 : out2);
#pragma unroll
        for (int i = 0; i < 4; i++) {
            int m = m0 + ty * 4 + i;
            if (m < Mc) {
                int bb = m / NTOK;
                int nn = m - bb * NTOK;
                float4 r;
                r.x = (acc[i][0] + bsum[0]) * scale;
                r.y = (acc[i][1] + bsum[1]) * scale;
                r.z = (acc[i][2] + bsum[2]) * scale;
                r.w = (acc[i][3] + bsum[3]) * scale;
                *(float4*)&dst[(((size_t)bb * NHEAD + h) * NTOK + nn) * 64 + tx * 4] = r;
            }
        }
    } else {
#pragma unroll
        for (int i = 0; i < 4; i++) {
            int m = m0 + ty * 4 + i;
            if (m < Mc) {
                float4 r;
                r.x = acc[i][0] + bias1[n0 + tx * 4 + 0];
                r.y = acc[i][1] + bias1[n0 + tx * 4 + 1];
                r.z = acc[i][2] + bias1[n0 + tx * 4 + 2];
                r.w = acc[i][3] + bias1[n0 + tx * 4 + 3];
                *(float4*)&out0[(size_t)m * 768 + n0 + tx * 4] = r;
            }
        }
    }
}

// ---------------------------------------------------------------------------
// K2: flash-style attention per (chunk-local b, h, 64-row q-tile).
//   S-tile (64x64) register GEMM; online softmax via 16-lane shfl groups;
//   P^T aliased into the K LDS buffer; PV second LDS GEMM. LDS ~50 KB.
//   R3 FIX: stage FULL 64x64 tiles (4 float4 per thread, d0 covers 0..60);
//   the R2 version staged only d<16 and read uninitialized LDS -> NaN.
// ---------------------------------------------------------------------------
__global__ __launch_bounds__(256) void attn_kernel(
    const float* __restrict__ Q, const float* __restrict__ K,
    const float* __restrict__ V, const float* __restrict__ BIAS,
    float* __restrict__ AO) {
    __shared__ float Qs[64][64];    // [d][row]
    __shared__ float KPs[64][68];   // K as [d][key]; later P^T as [key][row]
    __shared__ float Vs[64][68];    // [key][d]

    const int t  = threadIdx.x;
    const int tx = t & 15;
    const int ty = t >> 4;
    const int qt = blockIdx.x;          // 0..3
    const int bh = blockIdx.y;          // 0..Bc*12-1
    const int b  = bh / NHEAD;
    const int h  = bh - b * NHEAD;
    const int q0 = qt * 64;

    const float* qbase = Q + (size_t)bh * NTOK * 64;
    const float* kbase = K + (size_t)bh * NTOK * 64;
    const float* vbase = V + (size_t)bh * NTOK * 64;
    const float* bbase = BIAS + (size_t)h * NTOK * BIAS_PAD;

    const int lrow = t >> 2;   // 0..63
    const int lcg  = t & 3;    // 0..3

    {   // stage Q tile transposed [d][row], all 64 d per row
        const bool qvalid = (q0 + lrow < NTOK);
#pragma unroll
        for (int c4 = 0; c4 < 4; c4++) {
            const int d0 = (lcg + c4 * 4) * 4;      // 0..60 step 4, distinct
            float4 f = {0.f, 0.f, 0.f, 0.f};
            if (qvalid) f = *(const float4*)&qbase[(q0 + lrow) * 64 + d0];
            Qs[d0 + 0][lrow] = f.x;  Qs[d0 + 1][lrow] = f.y;
            Qs[d0 + 2][lrow] = f.z;  Qs[d0 + 3][lrow] = f.w;
        }
    }

    float O[4][4] = {};
    float m_run[4], l_run[4];
#pragma unroll
    for (int i = 0; i < 4; i++) { m_run[i] = -1e30f; l_run[i] = 0.f; }

    for (int kt = 0; kt < 4; kt++) {
        const int k0 = kt * 64;
        __syncthreads();   // Q staged / previous PV done before overwrite
        {
            const bool kvalid = (k0 + lrow < NTOK);
#pragma unroll
            for (int c4 = 0; c4 < 4; c4++) {
                const int d0 = (lcg + c4 * 4) * 4;
                float4 f = {0.f, 0.f, 0.f, 0.f}, g = {0.f, 0.f, 0.f, 0.f};
                if (kvalid) {
                    f = *(const float4*)&kbase[(k0 + lrow) * 64 + d0];
                    g = *(const float4*)&vbase[(k0 + lrow) * 64 + d0];
                }
                KPs[d0 + 0][lrow] = f.x;  KPs[d0 + 1][lrow] = f.y;
                KPs[d0 + 2][lrow] = f.z;  KPs[d0 + 3][lrow] = f.w;
                *(float4*)&Vs[lrow][d0] = g;
            }
        }
        __syncthreads();

        // ---- scores S = Q·K^T (inner dim d = 64) ----
        float s[4][4] = {};
#pragma unroll 8
        for (int dd = 0; dd < 64; dd++) {
            float4 a4 = *(const float4*)&Qs[dd][ty * 4];
            float4 b4 = *(const float4*)&KPs[dd][tx * 4];
            float av[4] = {a4.x, a4.y, a4.z, a4.w};
            float bv[4] = {b4.x, b4.y, b4.z, b4.w};
#pragma unroll
            for (int i = 0; i < 4; i++)
#pragma unroll
                for (int j = 0; j < 4; j++) s[i][j] += av[i] * bv[j];
        }

        // ---- + relative position bias, mask invalid keys ----
#pragma unroll
        for (int i = 0; i < 4; i++) {
            int qn = q0 + ty * 4 + i;
            float4 b4 = {0.f, 0.f, 0.f, 0.f};
            if (qn < NTOK) b4 = *(const float4*)&bbase[qn * BIAS_PAD + k0 + tx * 4];
            float bv[4] = {b4.x, b4.y, b4.z, b4.w};
#pragma unroll
            for (int j = 0; j < 4; j++) {
                int kn = k0 + tx * 4 + j;
                if (kn < NTOK) s[i][j] += bv[j];
                else           s[i][j] = -1e30f;
            }
        }

        // ---- online softmax (16-lane groups share a row) ----
#pragma unroll
        for (int i = 0; i < 4; i++) {
            float mx = fmaxf(fmaxf(s[i][0], s[i][1]), fmaxf(s[i][2], s[i][3]));
#pragma unroll
            for (int off = 1; off < 16; off <<= 1) mx = fmaxf(mx, __shfl_xor(mx, off));
            float mnew = fmaxf(m_run[i], mx);
            float al   = __expf(m_run[i] - mnew);
            m_run[i]   = mnew;
            float ts = 0.f;
#pragma unroll
            for (int j = 0; j < 4; j++) { s[i][j] = __expf(s[i][j] - mnew); ts += s[i][j]; }
#pragma unroll
            for (int off = 1; off < 16; off <<= 1) ts += __shfl_xor(ts, off);
            l_run[i] = l_run[i] * al + ts;
#pragma unroll
            for (int j = 0; j < 4; j++) O[i][j] *= al;
        }

        __syncthreads();   // all waves done reading K region
        // ---- write P^T into KPs: [key][row] ----
#pragma unroll
        for (int j = 0; j < 4; j++) {
            float4 p4 = make_float4(s[0][j], s[1][j], s[2][j], s[3][j]);
            *(float4*)&KPs[tx * 4 + j][ty * 4] = p4;
        }
        __syncthreads();

        // ---- O += P·V (inner dim = 64 keys) ----
#pragma unroll 8
        for (int l = 0; l < 64; l++) {
            float4 a4 = *(const float4*)&KPs[l][ty * 4];
            float4 b4 = *(const float4*)&Vs[l][tx * 4];
            float av[4] = {a4.x, a4.y, a4.z, a4.w};
            float bv[4] = {b4.x, b4.y, b4.z, b4.w};
#pragma unroll
            for (int i = 0; i < 4; i++)
#pragma unroll
                for (int j = 0; j < 4; j++) O[i][j] += av[i] * bv[j];
        }
    }

    // ---- epilogue: normalize + store chunk-local [Bc,N,768] ----
#pragma unroll
    for (int i = 0; i < 4; i++) {
        int qn = q0 + ty * 4 + i;
        if (qn < NTOK) {
            float r = 1.f / l_run[i];
            float4 o = make_float4(O[i][0] * r, O[i][1] * r, O[i][2] * r, O[i][3] * r);
            *(float4*)&AO[((size_t)b * NTOK + qn) * 768 + h * 64 + tx * 4] = o;
        }
    }
}

// ---------------------------------------------------------------------------
extern "C" void kernel_launch(void* const* d_in, const int* in_sizes, int n_in,
                              void* d_out, int out_size, void* d_ws, size_t ws_size,
                              hipStream_t stream) {
    const float* x      = (const float*)d_in[0];
    const float* qkv_w  = (const float*)d_in[1];
    const float* q_bias = (const float*)d_in[2];
    const float* v_bias = (const float*)d_in[3];
    const float* rpb    = (const float*)d_in[4];
    const float* proj_w = (const float*)d_in[5];
    const float* proj_b = (const float*)d_in[6];
    const int*   rel_idx = (const int*)d_in[7];
    float* out = (float*)d_out;

    const size_t EB    = 151296;                 // 12*197*64 == 197*768, per-batch elems
    const size_t Ebias = (size_t)NHEAD * NTOK * BIAS_PAD;   // 605,184

    // Adaptive chunk: kernels serialize on the stream, so q/k/v/ao regions are
    // reused across chunks. need(Bc) = (4*Bc*EB + Ebias)*4 bytes.
    int Bc = BATCH;
    while (Bc > 1 && (4 * (size_t)Bc * EB + Ebias) * sizeof(float) > ws_size) Bc >>= 1;
    if ((4 * (size_t)Bc * EB + Ebias) * sizeof(float) > ws_size) return; // ws < 4.9 MB
    const int nc = BATCH / Bc;
    const int Mc = Bc * NTOK;
    const int Gy = (Mc + 63) / 64;

    float* bias_full = (float*)d_ws;             // [12][197][256]
    float* q  = bias_full + Ebias;               // [Bc,12,197,64] each
    float* k  = q + (size_t)Bc * EB;
    float* v  = k + (size_t)Bc * EB;
    float* ao = v + (size_t)Bc * EB;             // [Bc,197,768]

    bias_precompute<<<((int)(NHEAD * NTOK * BIAS_PAD) + 255) / 256, 256, 0, stream>>>(
        rpb, rel_idx, bias_full);

    for (int c = 0; c < nc; c++) {
        const float* xc = x + (size_t)c * Mc * 768;
        gemm_nt<0><<<dim3(2304 / 64, Gy), 256, 0, stream>>>(
            xc, qkv_w, q_bias, v_bias, q, k, v, Mc);
        attn_kernel<<<dim3(4, Bc * NHEAD), 256, 0, stream>>>(q, k, v, bias_full, ao);
        gemm_nt<1><<<dim3(768 / 64, Gy), 256, 0, stream>>>(
            ao, proj_w, proj_b, nullptr, out + (size_t)c * Mc * 768, nullptr, nullptr, Mc);
    }
}

// Round 4
// 771.172 us; speedup vs baseline: 2.6552x; 2.6552x over previous
//
#include <hip/hip_runtime.h>
#include <hip/hip_bf16.h>
#include <cstdint>

// Problem constants (ViT-Base, 14x14 window + CLS)
#define BATCH 128
#define NTOK  197
#define NHEAD 12
#define HDIM  64
#define BIAS_PAD 256

typedef __attribute__((ext_vector_type(8))) __bf16 bf16x8;
typedef __attribute__((ext_vector_type(4))) float f32x4;
typedef __attribute__((ext_vector_type(4))) unsigned short ushort4v;

__device__ __forceinline__ unsigned short f2bf(float f) {
    union { float f; unsigned int u; } v; v.f = f;
    unsigned int r = (v.u + 0x7FFFu + ((v.u >> 16) & 1u)) >> 16;   // round-nearest-even
    return (unsigned short)r;
}

// async global->LDS 16B per lane; LDS dest is wave-uniform base + lane*16
__device__ __forceinline__ void async_cp16(const void* gsrc, void* lds_dst) {
    __builtin_amdgcn_global_load_lds(
        (const __attribute__((address_space(1))) unsigned int*)((uintptr_t)gsrc),
        (__attribute__((address_space(3))) unsigned int*)((uintptr_t)lds_dst),
        16, 0, 0);
}

// ---------------------------------------------------------------------------
// K0: densify relative-position bias (fp32, [12][197][256], zero pad)
// ---------------------------------------------------------------------------
__global__ void bias_precompute(const float* __restrict__ rpb,
                                const int* __restrict__ rel_idx,
                                float* __restrict__ bias_full) {
    int idx = blockIdx.x * 256 + threadIdx.x;
    const int per_h = NTOK * BIAS_PAD;
    if (idx >= NHEAD * per_h) return;
    int h   = idx / per_h;
    int rem = idx - h * per_h;
    int qn  = rem >> 8;
    int kn  = rem & 255;
    float v = 0.f;
    if (kn < NTOK) v = rpb[rel_idx[qn * NTOK + kn] * NHEAD + h];
    bias_full[idx] = v;
}

// ---------------------------------------------------------------------------
// fp32 -> bf16 (RNE), vectorized x4
// ---------------------------------------------------------------------------
__global__ __launch_bounds__(256) void cvt_bf16(const float4* __restrict__ src,
                                                ushort4v* __restrict__ dst, int n4) {
    int i = blockIdx.x * 256 + threadIdx.x;
    if (i >= n4) return;
    float4 f = src[i];
    ushort4v o;
    o.x = f2bf(f.x); o.y = f2bf(f.y); o.z = f2bf(f.z); o.w = f2bf(f.w);
    dst[i] = o;
}

// ---------------------------------------------------------------------------
// bf16 MFMA NT GEMM: C[m][n] = sum_k A[m][k]*W[n][k], K=768, fp32 accum/out.
// 128x128 tile / 256 threads (4 waves, 2x2), BK=32, 16x16x32 MFMA, 4x4
// tiles/wave. LDS [128][32] bf16 row-major (UNPADDED - global_load_lds needs
// lane-contiguous dest). Fragments: A/B lane = (m|n)=lane&15, k=quad*8+j;
// C/D col=lane&15, row=quad*4+reg (m89-verified).
// EPI=0: + qkv bias, q*=0.125, scatter to q/k/v fp32 [Bc,H,N,64]
// EPI=1: + proj bias -> out fp32 [m][768]
// ---------------------------------------------------------------------------
template <int EPI>
__global__ __launch_bounds__(256) void gemm_mfma(
    const unsigned short* __restrict__ A,   // [Mc][768] bf16 bits
    const unsigned short* __restrict__ W,   // [Nn][768] bf16 bits
    const float* __restrict__ bias1, const float* __restrict__ bias2,
    float* __restrict__ out0, float* __restrict__ out1, float* __restrict__ out2,
    int Mc) {
    __shared__ unsigned short As[128 * 32];
    __shared__ unsigned short Bs[128 * 32];

    const int t    = threadIdx.x;
    const int lane = t & 63;
    const int wave = t >> 6;       // 0..3
    const int wm   = wave >> 1;    // m half
    const int wn   = wave & 1;     // n half
    const int quad = lane >> 4;
    const int l16  = lane & 15;
    const int m0   = blockIdx.y * 128;
    const int n0   = blockIdx.x * 128;

    // staging: wave w covers rows w*32..w*32+32 (2 issues of 16 rows);
    // lane -> row = lane>>2, 16B col group = lane&3
    const int srow = lane >> 2;
    const int scol = (lane & 3) * 8;
    int ar0 = m0 + wave * 32 + srow;      if (ar0 >= Mc) ar0 = Mc - 1;
    int ar1 = m0 + wave * 32 + 16 + srow; if (ar1 >= Mc) ar1 = Mc - 1;
    const unsigned short* Ag0 = A + (size_t)ar0 * 768 + scol;
    const unsigned short* Ag1 = A + (size_t)ar1 * 768 + scol;
    const unsigned short* Wg0 = W + (size_t)(n0 + wave * 32 + srow) * 768 + scol;
    const unsigned short* Wg1 = Wg0 + (size_t)16 * 768;
    unsigned short* Ad0 = As + (wave * 32) * 32;
    unsigned short* Ad1 = As + (wave * 32 + 16) * 32;
    unsigned short* Bd0 = Bs + (wave * 32) * 32;
    unsigned short* Bd1 = Bs + (wave * 32 + 16) * 32;

    const unsigned short* Afp = As + (wm * 64 + l16) * 32 + quad * 8;
    const unsigned short* Bfp = Bs + (wn * 64 + l16) * 32 + quad * 8;

    f32x4 acc[4][4] = {};

    for (int k0 = 0; k0 < 768; k0 += 32) {
        __syncthreads();                       // prev frag reads done
        async_cp16(Ag0 + k0, Ad0);
        async_cp16(Ag1 + k0, Ad1);
        async_cp16(Wg0 + k0, Bd0);
        async_cp16(Wg1 + k0, Bd1);
        __syncthreads();                       // drains vmcnt -> LDS visible
        bf16x8 af[4], bfr[4];
#pragma unroll
        for (int i = 0; i < 4; i++) af[i]  = *(const bf16x8*)(Afp + i * 16 * 32);
#pragma unroll
        for (int j = 0; j < 4; j++) bfr[j] = *(const bf16x8*)(Bfp + j * 16 * 32);
#pragma unroll
        for (int i = 0; i < 4; i++)
#pragma unroll
            for (int j = 0; j < 4; j++)
                acc[i][j] = __builtin_amdgcn_mfma_f32_16x16x32_bf16(
                    af[i], bfr[j], acc[i][j], 0, 0, 0);
    }

    if (EPI == 0) {
        const int part   = n0 / 768;           // 768 % 128 == 0: uniform per block
        const float scale = (part == 0) ? 0.125f : 1.f;
        float* dst = (part == 0) ? out0 : (part == 1 ? out1 : out2);
        const int nb0 = n0 - part * 768;
#pragma unroll
        for (int j = 0; j < 4; j++) {
            const int nnb = nb0 + wn * 64 + j * 16;    // mult of 16; head-uniform
            const int h   = nnb >> 6;
            const int d   = (nnb & 63) + l16;
            const float bb = (part == 0) ? bias1[nnb + l16]
                           : (part == 2 ? bias2[nnb + l16] : 0.f);
#pragma unroll
            for (int i = 0; i < 4; i++) {
                const int mb = m0 + wm * 64 + i * 16 + quad * 4;
#pragma unroll
                for (int r = 0; r < 4; r++) {
                    const int m = mb + r;
                    if (m < Mc) {
                        const int bi  = m / NTOK;
                        const int tok = m - bi * NTOK;
                        dst[(((size_t)bi * NHEAD + h) * NTOK + tok) * 64 + d] =
                            (acc[i][j][r] + bb) * scale;
                    }
                }
            }
        }
    } else {
#pragma unroll
        for (int j = 0; j < 4; j++) {
            const int col = n0 + wn * 64 + j * 16 + l16;
            const float bb = bias1[col];
#pragma unroll
            for (int i = 0; i < 4; i++) {
                const int mb = m0 + wm * 64 + i * 16 + quad * 4;
#pragma unroll
                for (int r = 0; r < 4; r++) {
                    const int m = mb + r;
                    if (m < Mc) out0[(size_t)m * 768 + col] = acc[i][j][r] + bb;
                }
            }
        }
    }
}

// ---------------------------------------------------------------------------
// K2: flash-style fp32 attention (verified R3), now writing bf16 AO.
// ---------------------------------------------------------------------------
__global__ __launch_bounds__(256) void attn_kernel(
    const float* __restrict__ Q, const float* __restrict__ K,
    const float* __restrict__ V, const float* __restrict__ BIAS,
    unsigned short* __restrict__ AO) {
    __shared__ float Qs[64][64];    // [d][row]
    __shared__ float KPs[64][68];   // K as [d][key]; later P^T as [key][row]
    __shared__ float Vs[64][68];    // [key][d]

    const int t  = threadIdx.x;
    const int tx = t & 15;
    const int ty = t >> 4;
    const int qt = blockIdx.x;
    const int bh = blockIdx.y;
    const int b  = bh / NHEAD;
    const int h  = bh - b * NHEAD;
    const int q0 = qt * 64;

    const float* qbase = Q + (size_t)bh * NTOK * 64;
    const float* kbase = K + (size_t)bh * NTOK * 64;
    const float* vbase = V + (size_t)bh * NTOK * 64;
    const float* bbase = BIAS + (size_t)h * NTOK * BIAS_PAD;

    const int lrow = t >> 2;
    const int lcg  = t & 3;

    {   // stage Q tile transposed [d][row], all 64 d
        const bool qvalid = (q0 + lrow < NTOK);
#pragma unroll
        for (int c4 = 0; c4 < 4; c4++) {
            const int d0 = (lcg + c4 * 4) * 4;
            float4 f = {0.f, 0.f, 0.f, 0.f};
            if (qvalid) f = *(const float4*)&qbase[(q0 + lrow) * 64 + d0];
            Qs[d0 + 0][lrow] = f.x;  Qs[d0 + 1][lrow] = f.y;
            Qs[d0 + 2][lrow] = f.z;  Qs[d0 + 3][lrow] = f.w;
        }
    }

    float O[4][4] = {};
    float m_run[4], l_run[4];
#pragma unroll
    for (int i = 0; i < 4; i++) { m_run[i] = -1e30f; l_run[i] = 0.f; }

    for (int kt = 0; kt < 4; kt++) {
        const int k0 = kt * 64;
        __syncthreads();
        {
            const bool kvalid = (k0 + lrow < NTOK);
#pragma unroll
            for (int c4 = 0; c4 < 4; c4++) {
                const int d0 = (lcg + c4 * 4) * 4;
                float4 f = {0.f, 0.f, 0.f, 0.f}, g = {0.f, 0.f, 0.f, 0.f};
                if (kvalid) {
                    f = *(const float4*)&kbase[(k0 + lrow) * 64 + d0];
                    g = *(const float4*)&vbase[(k0 + lrow) * 64 + d0];
                }
                KPs[d0 + 0][lrow] = f.x;  KPs[d0 + 1][lrow] = f.y;
                KPs[d0 + 2][lrow] = f.z;  KPs[d0 + 3][lrow] = f.w;
                *(float4*)&Vs[lrow][d0] = g;
            }
        }
        __syncthreads();

        float s[4][4] = {};
#pragma unroll 8
        for (int dd = 0; dd < 64; dd++) {
            float4 a4 = *(const float4*)&Qs[dd][ty * 4];
            float4 b4 = *(const float4*)&KPs[dd][tx * 4];
            float av[4] = {a4.x, a4.y, a4.z, a4.w};
            float bv[4] = {b4.x, b4.y, b4.z, b4.w};
#pragma unroll
            for (int i = 0; i < 4; i++)
#pragma unroll
                for (int j = 0; j < 4; j++) s[i][j] += av[i] * bv[j];
        }

#pragma unroll
        for (int i = 0; i < 4; i++) {
            int qn = q0 + ty * 4 + i;
            float4 b4 = {0.f, 0.f, 0.f, 0.f};
            if (qn < NTOK) b4 = *(const float4*)&bbase[qn * BIAS_PAD + k0 + tx * 4];
            float bv[4] = {b4.x, b4.y, b4.z, b4.w};
#pragma unroll
            for (int j = 0; j < 4; j++) {
                int kn = k0 + tx * 4 + j;
                if (kn < NTOK) s[i][j] += bv[j];
                else           s[i][j] = -1e30f;
            }
        }

#pragma unroll
        for (int i = 0; i < 4; i++) {
            float mx = fmaxf(fmaxf(s[i][0], s[i][1]), fmaxf(s[i][2], s[i][3]));
#pragma unroll
            for (int off = 1; off < 16; off <<= 1) mx = fmaxf(mx, __shfl_xor(mx, off));
            float mnew = fmaxf(m_run[i], mx);
            float al   = __expf(m_run[i] - mnew);
            m_run[i]   = mnew;
            float ts = 0.f;
#pragma unroll
            for (int j = 0; j < 4; j++) { s[i][j] = __expf(s[i][j] - mnew); ts += s[i][j]; }
#pragma unroll
            for (int off = 1; off < 16; off <<= 1) ts += __shfl_xor(ts, off);
            l_run[i] = l_run[i] * al + ts;
#pragma unroll
            for (int j = 0; j < 4; j++) O[i][j] *= al;
        }

        __syncthreads();
#pragma unroll
        for (int j = 0; j < 4; j++) {
            float4 p4 = make_float4(s[0][j], s[1][j], s[2][j], s[3][j]);
            *(float4*)&KPs[tx * 4 + j][ty * 4] = p4;
        }
        __syncthreads();

#pragma unroll 8
        for (int l = 0; l < 64; l++) {
            float4 a4 = *(const float4*)&KPs[l][ty * 4];
            float4 b4 = *(const float4*)&Vs[l][tx * 4];
            float av[4] = {a4.x, a4.y, a4.z, a4.w};
            float bv[4] = {b4.x, b4.y, b4.z, b4.w};
#pragma unroll
            for (int i = 0; i < 4; i++)
#pragma unroll
                for (int j = 0; j < 4; j++) O[i][j] += av[i] * bv[j];
        }
    }

#pragma unroll
    for (int i = 0; i < 4; i++) {
        int qn = q0 + ty * 4 + i;
        if (qn < NTOK) {
            float r = 1.f / l_run[i];
            ushort4v o;
            o.x = f2bf(O[i][0] * r); o.y = f2bf(O[i][1] * r);
            o.z = f2bf(O[i][2] * r); o.w = f2bf(O[i][3] * r);
            *(ushort4v*)&AO[((size_t)b * NTOK + qn) * 768 + h * 64 + tx * 4] = o;
        }
    }
}

// ---------------------------------------------------------------------------
extern "C" void kernel_launch(void* const* d_in, const int* in_sizes, int n_in,
                              void* d_out, int out_size, void* d_ws, size_t ws_size,
                              hipStream_t stream) {
    const float* x      = (const float*)d_in[0];
    const float* qkv_w  = (const float*)d_in[1];
    const float* q_bias = (const float*)d_in[2];
    const float* v_bias = (const float*)d_in[3];
    const float* rpb    = (const float*)d_in[4];
    const float* proj_w = (const float*)d_in[5];
    const float* proj_b = (const float*)d_in[6];
    const int*   rel_idx = (const int*)d_in[7];
    float* out = (float*)d_out;

    const size_t EB    = 151296;                              // 12*197*64 = 197*768
    const size_t Ebias = (size_t)NHEAD * NTOK * BIAS_PAD;     // 605,184 floats
    const size_t NX    = (size_t)BATCH * NTOK * 768;          // 19,365,888
    const size_t NWQ   = (size_t)2304 * 768;                  // 1,769,472
    const size_t NWP   = (size_t)768 * 768;                   //   589,824

    // layout: bias(f32) | xbf | wqkv_bf | wproj_bf | q,k,v (f32) | ao (bf16)
    const size_t fixed_bytes = Ebias * 4 + (NX + NWQ + NWP) * 2;
    int Bc = BATCH;
    while (Bc > 1 && fixed_bytes + 14ull * Bc * EB > ws_size) Bc >>= 1;
    if (fixed_bytes + 14ull * Bc * EB > ws_size) return;
    const int nc = BATCH / Bc;
    const int Mc = Bc * NTOK;
    const int Gy = (Mc + 127) / 128;

    float* bias_full      = (float*)d_ws;
    unsigned short* xbf   = (unsigned short*)(bias_full + Ebias);
    unsigned short* wqkv  = xbf + NX;
    unsigned short* wproj = wqkv + NWQ;
    float* q  = (float*)(wproj + NWP);
    float* k  = q + (size_t)Bc * EB;
    float* v  = k + (size_t)Bc * EB;
    unsigned short* aobf = (unsigned short*)(v + (size_t)Bc * EB);

    bias_precompute<<<((int)(NHEAD * NTOK * BIAS_PAD) + 255) / 256, 256, 0, stream>>>(
        rpb, rel_idx, bias_full);
    cvt_bf16<<<(int)((NX / 4 + 255) / 256), 256, 0, stream>>>(
        (const float4*)x, (ushort4v*)xbf, (int)(NX / 4));
    cvt_bf16<<<(int)((NWQ / 4 + 255) / 256), 256, 0, stream>>>(
        (const float4*)qkv_w, (ushort4v*)wqkv, (int)(NWQ / 4));
    cvt_bf16<<<(int)((NWP / 4 + 255) / 256), 256, 0, stream>>>(
        (const float4*)proj_w, (ushort4v*)wproj, (int)(NWP / 4));

    for (int c = 0; c < nc; c++) {
        gemm_mfma<0><<<dim3(2304 / 128, Gy), 256, 0, stream>>>(
            xbf + (size_t)c * Mc * 768, wqkv, q_bias, v_bias, q, k, v, Mc);
        attn_kernel<<<dim3(4, Bc * NHEAD), 256, 0, stream>>>(q, k, v, bias_full, aobf);
        gemm_mfma<1><<<dim3(768 / 128, Gy), 256, 0, stream>>>(
            aobf, wproj, proj_b, nullptr, out + (size_t)c * Mc * 768, nullptr, nullptr, Mc);
    }
}

// Round 5
// 471.033 us; speedup vs baseline: 4.3471x; 1.6372x over previous
//
#include <hip/hip_runtime.h>
#include <hip/hip_bf16.h>
#include <cstdint>

// Problem constants (ViT-Base, 14x14 window + CLS)
#define BATCH 128
#define NTOK  197
#define NHEAD 12

typedef __attribute__((ext_vector_type(8))) __bf16 bf16x8;
typedef __attribute__((ext_vector_type(4))) float f32x4;
typedef __attribute__((ext_vector_type(4))) unsigned short ushort4v;

#define KSTR 72   // LDS row stride (bf16 elems) for attn tiles: uniform banks

__device__ __forceinline__ unsigned short f2bf(float f) {
    union { float f; unsigned int u; } v; v.f = f;
    unsigned int r = (v.u + 0x7FFFu + ((v.u >> 16) & 1u)) >> 16;   // RNE
    return (unsigned short)r;
}

// async global->LDS 16B per lane; LDS dest wave-uniform base + lane*16
__device__ __forceinline__ void async_cp16(const void* gsrc, void* lds_dst) {
    __builtin_amdgcn_global_load_lds(
        (const __attribute__((address_space(1))) unsigned int*)((uintptr_t)gsrc),
        (__attribute__((address_space(3))) unsigned int*)((uintptr_t)lds_dst),
        16, 0, 0);
}

// ---------------------------------------------------------------------------
// K0: bias in MFMA C/D fragment order:
//   BT[h][qt16][kt][quad][l16][j*4+r] = rpb[rel_idx[qn][kn]][h]
//   qn = qt16*16+quad*4+r (clamped), kn = kt*64+j*16+l16 (0 if >=197)
//   total 12*16*4*4*16*16 = 786432 floats (3 MB, L2-resident)
// ---------------------------------------------------------------------------
__global__ void bias_tiles(const float* __restrict__ rpb,
                           const int* __restrict__ rel_idx,
                           float* __restrict__ BT) {
    int idx = blockIdx.x * 256 + threadIdx.x;          // exactly 786432
    int r    = idx & 3;
    int j    = (idx >> 2) & 3;
    int l16  = (idx >> 4) & 15;
    int quad = (idx >> 8) & 3;
    int kt   = (idx >> 10) & 3;
    int qt   = (idx >> 12) & 15;
    int h    = idx >> 16;                              // 0..11
    int qn = qt * 16 + quad * 4 + r; if (qn > 196) qn = 196;
    int kn = kt * 64 + j * 16 + l16;
    float v = 0.f;
    if (kn < NTOK) v = rpb[rel_idx[qn * NTOK + kn] * NHEAD + h];
    BT[idx] = v;
}

// ---------------------------------------------------------------------------
// fp32 -> bf16 (RNE), vectorized x4
// ---------------------------------------------------------------------------
__global__ __launch_bounds__(256) void cvt_bf16(const float4* __restrict__ src,
                                                ushort4v* __restrict__ dst, int n4) {
    int i = blockIdx.x * 256 + threadIdx.x;
    if (i >= n4) return;
    float4 f = src[i];
    ushort4v o;
    o.x = f2bf(f.x); o.y = f2bf(f.y); o.z = f2bf(f.z); o.w = f2bf(f.w);
    dst[i] = o;
}

// ---------------------------------------------------------------------------
// bf16 MFMA NT GEMM (m97 structure), K=768, fp32 accum.
// EPI=0: +qkv bias, q*=0.125, scatter BF16 q/k/v [Bc,H,N,64]
// EPI=1: +proj bias -> fp32 out [m][768]
// ---------------------------------------------------------------------------
template <int EPI>
__global__ __launch_bounds__(256) void gemm_mfma(
    const unsigned short* __restrict__ A,   // [Mc][768] bf16
    const unsigned short* __restrict__ W,   // [Nn][768] bf16
    const float* __restrict__ bias1, const float* __restrict__ bias2,
    unsigned short* __restrict__ oq, unsigned short* __restrict__ ok,
    unsigned short* __restrict__ ov, float* __restrict__ outf,
    int Mc) {
    __shared__ unsigned short As[128 * 32];
    __shared__ unsigned short Bs[128 * 32];

    const int t    = threadIdx.x;
    const int lane = t & 63;
    const int wave = t >> 6;
    const int wm   = wave >> 1;
    const int wn   = wave & 1;
    const int quad = lane >> 4;
    const int l16  = lane & 15;
    const int m0   = blockIdx.y * 128;
    const int n0   = blockIdx.x * 128;

    const int srow = lane >> 2;
    const int scol = (lane & 3) * 8;
    int ar0 = m0 + wave * 32 + srow;      if (ar0 >= Mc) ar0 = Mc - 1;
    int ar1 = m0 + wave * 32 + 16 + srow; if (ar1 >= Mc) ar1 = Mc - 1;
    const unsigned short* Ag0 = A + (size_t)ar0 * 768 + scol;
    const unsigned short* Ag1 = A + (size_t)ar1 * 768 + scol;
    const unsigned short* Wg0 = W + (size_t)(n0 + wave * 32 + srow) * 768 + scol;
    const unsigned short* Wg1 = Wg0 + (size_t)16 * 768;
    unsigned short* Ad0 = As + (wave * 32) * 32;
    unsigned short* Ad1 = As + (wave * 32 + 16) * 32;
    unsigned short* Bd0 = Bs + (wave * 32) * 32;
    unsigned short* Bd1 = Bs + (wave * 32 + 16) * 32;

    const unsigned short* Afp = As + (wm * 64 + l16) * 32 + quad * 8;
    const unsigned short* Bfp = Bs + (wn * 64 + l16) * 32 + quad * 8;

    f32x4 acc[4][4] = {};

    for (int k0 = 0; k0 < 768; k0 += 32) {
        __syncthreads();
        async_cp16(Ag0 + k0, Ad0);
        async_cp16(Ag1 + k0, Ad1);
        async_cp16(Wg0 + k0, Bd0);
        async_cp16(Wg1 + k0, Bd1);
        __syncthreads();
        bf16x8 af[4], bfr[4];
#pragma unroll
        for (int i = 0; i < 4; i++) af[i]  = *(const bf16x8*)(Afp + i * 16 * 32);
#pragma unroll
        for (int j = 0; j < 4; j++) bfr[j] = *(const bf16x8*)(Bfp + j * 16 * 32);
#pragma unroll
        for (int i = 0; i < 4; i++)
#pragma unroll
            for (int j = 0; j < 4; j++)
                acc[i][j] = __builtin_amdgcn_mfma_f32_16x16x32_bf16(
                    af[i], bfr[j], acc[i][j], 0, 0, 0);
    }

    if (EPI == 0) {
        const int part   = n0 / 768;
        const float scale = (part == 0) ? 0.125f : 1.f;
        unsigned short* dst = (part == 0) ? oq : (part == 1 ? ok : ov);
        const int nb0 = n0 - part * 768;
#pragma unroll
        for (int j = 0; j < 4; j++) {
            const int nnb = nb0 + wn * 64 + j * 16;
            const int h   = nnb >> 6;
            const int d   = (nnb & 63) + l16;
            const float bb = (part == 0) ? bias1[nnb + l16]
                           : (part == 2 ? bias2[nnb + l16] : 0.f);
#pragma unroll
            for (int i = 0; i < 4; i++) {
                const int mb = m0 + wm * 64 + i * 16 + quad * 4;
#pragma unroll
                for (int r = 0; r < 4; r++) {
                    const int m = mb + r;
                    if (m < Mc) {
                        const int bi  = m / NTOK;
                        const int tok = m - bi * NTOK;
                        dst[(((size_t)bi * NHEAD + h) * NTOK + tok) * 64 + d] =
                            f2bf((acc[i][j][r] + bb) * scale);
                    }
                }
            }
        }
    } else {
#pragma unroll
        for (int j = 0; j < 4; j++) {
            const int col = n0 + wn * 64 + j * 16 + l16;
            const float bb = bias1[col];
#pragma unroll
            for (int i = 0; i < 4; i++) {
                const int mb = m0 + wm * 64 + i * 16 + quad * 4;
#pragma unroll
                for (int r = 0; r < 4; r++) {
                    const int m = mb + r;
                    if (m < Mc) outf[(size_t)m * 768 + col] = acc[i][j][r] + bb;
                }
            }
        }
    }
}

// ---------------------------------------------------------------------------
// K2: MFMA flash attention. One block per (b,h); 4 waves x 64 q-rows.
//   S = q.k^T (acc initialized with rpb fragments), fixed-max softmax,
//   P -> per-wave LDS (C/D -> A-layout), O += P.V via MFMA. Fp32 l-sum,
//   reduced once at the end. All LDS rows stride KSTR=72 (uniform banks).
// ---------------------------------------------------------------------------
__global__ __launch_bounds__(256, 2) void attn_mfma(
    const unsigned short* __restrict__ Q, const unsigned short* __restrict__ K,
    const unsigned short* __restrict__ V, const float* __restrict__ BT,
    unsigned short* __restrict__ AO) {
    __shared__ unsigned short Ks[64 * KSTR];       // K-tile  [key][d]
    __shared__ unsigned short Vt[64 * KSTR];       // V-tile^T [d][key]
    __shared__ unsigned short Ps[4][64 * KSTR];    // per-wave P [q][key]

    const int t    = threadIdx.x;
    const int lane = t & 63;
    const int wave = t >> 6;
    const int quad = lane >> 4;
    const int l16  = lane & 15;
    const int bh   = blockIdx.x;
    const int b    = bh / NHEAD;
    const int h    = bh - b * NHEAD;

    const unsigned short* qb = Q + (size_t)bh * NTOK * 64;
    const unsigned short* kb = K + (size_t)bh * NTOK * 64;
    const unsigned short* vb = V + (size_t)bh * NTOK * 64;

    // Q fragments in registers for the whole kernel (A-layout: m=l16, k=quad*8+j)
    bf16x8 qf[4][2];
#pragma unroll
    for (int i = 0; i < 4; i++) {
        int tok = wave * 64 + i * 16 + l16; if (tok > 196) tok = 196;
#pragma unroll
        for (int ks = 0; ks < 2; ks++)
            qf[i][ks] = *(const bf16x8*)&qb[(size_t)tok * 64 + ks * 32 + quad * 8];
    }

    f32x4 O[4][4] = {};
    float lsum[4][4] = {};        // [i][r]

    for (int kt = 0; kt < 4; kt++) {
        __syncthreads();          // prior iteration's Ks/Vt reads complete
        {   // stage Ks [key][d], stride 72: thread -> row t>>2, 32B chunk t&3
            const int row = t >> 2, cg = t & 3;
            int gk = kt * 64 + row; if (gk > 196) gk = 196;
            const uint4* src = (const uint4*)&kb[(size_t)gk * 64 + cg * 16];
            *(uint4*)&Ks[row * KSTR + cg * 16]     = src[0];
            *(uint4*)&Ks[row * KSTR + cg * 16 + 8] = src[1];
        }
        {   // stage Vt [d][key] transposed: thread -> key t&63, d-group t>>6
            const int key = t & 63, dg = t >> 6;
            int gk = kt * 64 + key; if (gk > 196) gk = 196;
            union { uint4 v4[2]; unsigned short u[16]; } tmp;
            const uint4* src = (const uint4*)&vb[(size_t)gk * 64 + dg * 16];
            tmp.v4[0] = src[0]; tmp.v4[1] = src[1];
#pragma unroll
            for (int u = 0; u < 16; u++) Vt[(dg * 16 + u) * KSTR + key] = tmp.u[u];
        }
        __syncthreads();

        // ---- acc init = rpb fragments (coalesced dwordx4, L2-hit) ----
        f32x4 acc[4][4];
#pragma unroll
        for (int i = 0; i < 4; i++) {
            const float4* bp = (const float4*)&BT[
                (((((size_t)h * 16 + (wave * 4 + i)) * 4 + kt) * 4 + quad) * 16 + l16) * 16];
#pragma unroll
            for (int j = 0; j < 4; j++) {
                float4 f = bp[j];
                acc[i][j] = (f32x4){f.x, f.y, f.z, f.w};
            }
        }

        // ---- S = q.k^T + bias ----
#pragma unroll
        for (int ks = 0; ks < 2; ks++) {
            bf16x8 kf[4];
#pragma unroll
            for (int j = 0; j < 4; j++)
                kf[j] = *(const bf16x8*)&Ks[(j * 16 + l16) * KSTR + ks * 32 + quad * 8];
#pragma unroll
            for (int i = 0; i < 4; i++)
#pragma unroll
                for (int j = 0; j < 4; j++)
                    acc[i][j] = __builtin_amdgcn_mfma_f32_16x16x32_bf16(
                        qf[i][ks], kf[j], acc[i][j], 0, 0, 0);
        }

        // ---- fixed-max softmax: p = exp(s), masked keys -> 0; write P ----
#pragma unroll
        for (int j = 0; j < 4; j++) {
            const int kn = kt * 64 + j * 16 + l16;
            const bool kval = (kn < NTOK);
#pragma unroll
            for (int i = 0; i < 4; i++)
#pragma unroll
                for (int r = 0; r < 4; r++) {
                    float p = kval ? __expf(fminf(acc[i][j][r], 30.f)) : 0.f;
                    lsum[i][r] += p;
                    Ps[wave][(i * 16 + quad * 4 + r) * KSTR + j * 16 + l16] = f2bf(p);
                }
        }
        // in-wave LDS write->read ordering: compiler inserts lgkmcnt; no barrier
        // needed (Ps[wave] is wave-private).

        // ---- O += P.V ----
#pragma unroll
        for (int ks = 0; ks < 2; ks++) {
            bf16x8 vf[4], pf[4];
#pragma unroll
            for (int jd = 0; jd < 4; jd++)
                vf[jd] = *(const bf16x8*)&Vt[(jd * 16 + l16) * KSTR + ks * 32 + quad * 8];
#pragma unroll
            for (int i = 0; i < 4; i++)
                pf[i] = *(const bf16x8*)&Ps[wave][(i * 16 + l16) * KSTR + ks * 32 + quad * 8];
#pragma unroll
            for (int i = 0; i < 4; i++)
#pragma unroll
                for (int jd = 0; jd < 4; jd++)
                    O[i][jd] = __builtin_amdgcn_mfma_f32_16x16x32_bf16(
                        pf[i], vf[jd], O[i][jd], 0, 0, 0);
        }
    }

    // ---- l-sum reduction across the 16-lane col groups, then store ----
#pragma unroll
    for (int i = 0; i < 4; i++)
#pragma unroll
        for (int r = 0; r < 4; r++) {
            float l = lsum[i][r];
            l += __shfl_xor(l, 1); l += __shfl_xor(l, 2);
            l += __shfl_xor(l, 4); l += __shfl_xor(l, 8);
            lsum[i][r] = 1.f / l;
        }
#pragma unroll
    for (int i = 0; i < 4; i++) {
        const int tb = wave * 64 + i * 16 + quad * 4;
#pragma unroll
        for (int r = 0; r < 4; r++) {
            const int tok = tb + r;
            if (tok < NTOK) {
                const float rl = lsum[i][r];
#pragma unroll
                for (int jd = 0; jd < 4; jd++)
                    AO[((size_t)b * NTOK + tok) * 768 + h * 64 + jd * 16 + l16] =
                        f2bf(O[i][jd][r] * rl);
            }
        }
    }
}

// ---------------------------------------------------------------------------
extern "C" void kernel_launch(void* const* d_in, const int* in_sizes, int n_in,
                              void* d_out, int out_size, void* d_ws, size_t ws_size,
                              hipStream_t stream) {
    const float* x      = (const float*)d_in[0];
    const float* qkv_w  = (const float*)d_in[1];
    const float* q_bias = (const float*)d_in[2];
    const float* v_bias = (const float*)d_in[3];
    const float* rpb    = (const float*)d_in[4];
    const float* proj_w = (const float*)d_in[5];
    const float* proj_b = (const float*)d_in[6];
    const int*   rel_idx = (const int*)d_in[7];
    float* out = (float*)d_out;

    const size_t EB   = 151296;                    // 12*197*64 = 197*768
    const size_t NBT  = 786432;                    // bias tiles (floats)
    const size_t NX   = (size_t)BATCH * NTOK * 768;
    const size_t NWQ  = (size_t)2304 * 768;
    const size_t NWP  = (size_t)768 * 768;

    // layout: BT(f32) | xbf | wqkv | wproj | q,k,v,ao (all bf16)
    const size_t fixed_bytes = NBT * 4 + (NX + NWQ + NWP) * 2;
    int Bc = BATCH;
    while (Bc > 1 && fixed_bytes + 8ull * Bc * EB > ws_size) Bc >>= 1;
    if (fixed_bytes + 8ull * Bc * EB > ws_size) return;
    const int nc = BATCH / Bc;
    const int Mc = Bc * NTOK;
    const int Gy = (Mc + 127) / 128;

    float* BT             = (float*)d_ws;
    unsigned short* xbf   = (unsigned short*)(BT + NBT);
    unsigned short* wqkv  = xbf + NX;
    unsigned short* wproj = wqkv + NWQ;
    unsigned short* q     = wproj + NWP;
    unsigned short* k     = q + (size_t)Bc * EB;
    unsigned short* v     = k + (size_t)Bc * EB;
    unsigned short* aobf  = v + (size_t)Bc * EB;

    bias_tiles<<<(int)(NBT / 256), 256, 0, stream>>>(rpb, rel_idx, BT);
    cvt_bf16<<<(int)((NX / 4 + 255) / 256), 256, 0, stream>>>(
        (const float4*)x, (ushort4v*)xbf, (int)(NX / 4));
    cvt_bf16<<<(int)((NWQ / 4 + 255) / 256), 256, 0, stream>>>(
        (const float4*)qkv_w, (ushort4v*)wqkv, (int)(NWQ / 4));
    cvt_bf16<<<(int)((NWP / 4 + 255) / 256), 256, 0, stream>>>(
        (const float4*)proj_w, (ushort4v*)wproj, (int)(NWP / 4));

    for (int c = 0; c < nc; c++) {
        gemm_mfma<0><<<dim3(2304 / 128, Gy), 256, 0, stream>>>(
            xbf + (size_t)c * Mc * 768, wqkv, q_bias, v_bias, q, k, v, nullptr, Mc);
        attn_mfma<<<Bc * NHEAD, 256, 0, stream>>>(q, k, v, BT, aobf);
        gemm_mfma<1><<<dim3(768 / 128, Gy), 256, 0, stream>>>(
            aobf, wproj, proj_b, nullptr, nullptr, nullptr, nullptr,
            out + (size_t)c * Mc * 768, Mc);
    }
}